// Round 9
// baseline (188.788 us; speedup 1.0000x reference)
//
#include <hip/hip_runtime.h>
#include <hip/hip_bf16.h>
#include <math.h>

#define CDIM 192
#define NHEADS 6
#define WIN 7
#define KWIN 49
#define BATCH 4
#define PIX 3136      // 56*56
#define NPIX 12544    // BATCH*PIX
#define NIMG 24       // BATCH*NHEADS
#define EPSV 1e-5f

typedef __bf16 bf16x8 __attribute__((ext_vector_type(8)));
typedef float f32x16 __attribute__((ext_vector_type(16)));
typedef unsigned int uint4v __attribute__((ext_vector_type(4)));
typedef unsigned short u16;

// ---------------- BN stats ---------------------------------------------------
__global__ __launch_bounds__(256) void bn_stats_k(const float* __restrict__ x,
                                                  float* __restrict__ stats) {
  int c = blockIdx.x;
  float s = 0.f, q = 0.f;
  for (int n = threadIdx.x; n < BATCH * PIX; n += 256) {
    int b = n / PIX, p = n - b * PIX;
    float v = x[((size_t)b * CDIM + c) * PIX + p];
    s += v; q += v * v;
  }
  __shared__ float rs[256], rq[256];
  rs[threadIdx.x] = s; rq[threadIdx.x] = q;
  __syncthreads();
  for (int st = 128; st > 0; st >>= 1) {
    if (threadIdx.x < st) { rs[threadIdx.x] += rs[threadIdx.x + st]; rq[threadIdx.x] += rq[threadIdx.x + st]; }
    __syncthreads();
  }
  if (threadIdx.x == 0) {
    float mean = rs[0] / (float)(BATCH * PIX);
    float var = rq[0] / (float)(BATCH * PIX) - mean * mean;
    stats[c] = mean;
    stats[CDIM + c] = rsqrtf(var + EPSV);
  }
}

// ------- fold BN + q-scale into qkv weights, writing PACKED frags directly --
__global__ __launch_bounds__(192) void fold_pack_k(
    const float* __restrict__ qkv_w, const float* __restrict__ qkv_b,
    const float* __restrict__ gamma, const float* __restrict__ beta,
    const float* __restrict__ stats, u16* __restrict__ pk_qkv,
    float* __restrict__ b_eff) {
  int o = blockIdx.x, c = threadIdx.x;
  float alpha = gamma[c] * stats[CDIM + c];
  float shift = beta[c] - stats[c] * alpha;
  float w = qkv_w[o * CDIM + c];
  float scale = (o < CDIM) ? 0.17677669529663687f : 1.f;
  int t8 = ((((o >> 5) * 12 + (c >> 4)) * 64 + (((c >> 3) & 1) * 32 + (o & 31))) << 3) + (c & 7);
  ((__hip_bfloat16*)pk_qkv)[t8] = __float2bfloat16(w * alpha * scale);
  __shared__ float r[CDIM];
  r[c] = w * shift;
  __syncthreads();
  if (c == 0) {
    float s = 0.f;
    for (int i = 0; i < CDIM; i++) s += r[i];
    b_eff[o] = (qkv_b[o] + s) * scale;
  }
}

// ---------------- generic pack helper: W[Cout][Cin] -> frag-major -----------
__device__ inline void pack_one(const float* __restrict__ W, u16* __restrict__ out,
                                int Cin, int t) {
  int lane = t & 63, rest = t >> 6;
  int nK = Cin >> 4;
  int kk = rest % nK, mtg = rest / nK;
  int o = mtg * 32 + (lane & 31), c = kk * 16 + (lane >> 5) * 8;
  const float* src = W + (size_t)o * Cin + c;
  __hip_bfloat16 tmp[8];
#pragma unroll
  for (int e = 0; e < 8; e++) tmp[e] = __float2bfloat16(src[e]);
  *(uint4v*)(out + (size_t)t * 8) = *(uint4v*)tmp;
}

// --------- merged prep: dm_w frag pack (784 blk) + proj/c1/c2 packs ---------
__global__ __launch_bounds__(256) void prep2_k(
    const float* __restrict__ dm_w, u16* __restrict__ wTb2,
    const float* __restrict__ proj_w, u16* __restrict__ pk_proj,
    const float* __restrict__ c1_w, u16* __restrict__ pk_c1,
    const float* __restrict__ c2_w, u16* __restrict__ pk_c2) {
  int bid = blockIdx.x, tid = threadIdx.x;
  if (bid < 784) {
    int idx = bid * 256 + tid;
    int e = idx & 7;
    int tmp = idx >> 3;
    int lane = tmp & 63; tmp >>= 6;
    int ch = tmp & 3; tmp >>= 2;
    int tap = tmp % 49, Mt = tmp / 49;
    int ko = Mt * 32 + (lane & 31);
    int ci = ch * 16 + (lane >> 5) * 8 + e;
    float v = (ko < KWIN) ? dm_w[(size_t)ko * 3136 + ci * 49 + tap] : 0.f;
    ((__hip_bfloat16*)wTb2)[idx] = __float2bfloat16(v);
  } else if (bid < 802) {
    int t = (bid - 784) * 256 + tid;
    if (t < 4608) pack_one(proj_w, pk_proj, 192, t);
  } else if (bid < 874) {
    int t = (bid - 802) * 256 + tid;
    if (t < 18432) pack_one(c1_w, pk_c1, 192, t);
  } else {
    int t = (bid - 874) * 256 + tid;
    if (t < 18432) pack_one(c2_w, pk_c2, 768, t);
  }
}

// ---------------- x [b][c][p] fp32 -> xT [b*p][192] bf16 --------------------
__global__ __launch_bounds__(256) void xT_k(const float* __restrict__ x,
                                            u16* __restrict__ xT) {
  __shared__ float Ls[64][33];
  int bb = blockIdx.x / 49;
  int p0 = (blockIdx.x % 49) * 64;
  int c0 = blockIdx.y * 32;
  int tid = threadIdx.x;
  int j = tid & 63;
#pragma unroll
  for (int it = 0; it < 8; it++) {
    int c = it * 4 + (tid >> 6);
    Ls[j][c] = x[((size_t)bb * CDIM + c0 + c) * PIX + p0 + j];
  }
  __syncthreads();
  int jr = tid >> 2, t = tid & 3;
  __hip_bfloat16 tmp[8];
#pragma unroll
  for (int u = 0; u < 8; u++) tmp[u] = __float2bfloat16(Ls[jr][t * 8 + u]);
  *(uint4v*)(xT + (size_t)(bb * PIX + p0 + jr) * CDIM + c0 + t * 8) = *(uint4v*)tmp;
}

// ---------------- MFMA GEMM, 128-px tile: Y[o][gp] = sum_c W[o][c]*Bm[gp][c] -
// 4 waves each own a 32-px strip x 64 o (Mt in acc). B-reads 1 per 2 MFMAs.
#define MG_QKV 0
#define MG_PROJ 1
#define MG_GELU 2
#define MG_C2 3
#define MGS2 1032   // g-plane stride u16 (128*8 + 8 pad)

template <int EPI>
__global__ __launch_bounds__(256, 4) void mgemm_k(
    const u16* __restrict__ Bm, const u16* __restrict__ Apk,
    const float* __restrict__ bias,
    float* __restrict__ outF, u16* __restrict__ outT, u16* __restrict__ outT2,
    const float* __restrict__ extra, int Cin) {
  __shared__ __align__(16) u16 Bs[8 * MGS2];  // 16.5 KB
  int tid = threadIdx.x;
  int lane = tid & 63, wid = tid >> 6;
  int hi = lane >> 5, ln31 = lane & 31;
  int p0 = blockIdx.x * 128;
  int o0 = blockIdx.y * 64;
  int nK = Cin >> 4;
  f32x16 acc[2];
#pragma unroll
  for (int mt = 0; mt < 2; mt++)
#pragma unroll
    for (int i = 0; i < 16; i++) acc[mt][i] = 0.f;

  for (int cc = 0; cc < Cin; cc += 64) {
#pragma unroll
    for (int i = 0; i < 4; i++) {
      int idx = i * 256 + tid;
      int g = idx & 7, p = idx >> 3;
      uint4v v = *(const uint4v*)(Bm + (size_t)(p0 + p) * Cin + cc + g * 8);
      *(uint4v*)&Bs[g * MGS2 + p * 8] = v;
    }
    __syncthreads();
    const u16* Ab = Apk + ((size_t)(o0 >> 5) * nK + (cc >> 4)) * 512 + lane * 8;
    int pA = wid * 32 + ln31;
#pragma unroll
    for (int ks = 0; ks < 4; ks++) {
      int g = ks * 2 + hi;
      bf16x8 b0 = *(const bf16x8*)&Bs[g * MGS2 + pA * 8];
      bf16x8 a0 = *(const bf16x8*)(Ab + ks * 512);
      bf16x8 a1 = *(const bf16x8*)(Ab + (nK + ks) * 512);
      acc[0] = __builtin_amdgcn_mfma_f32_32x32x16_bf16(a0, b0, acc[0], 0, 0, 0);
      acc[1] = __builtin_amdgcn_mfma_f32_32x32x16_bf16(a1, b0, acc[1], 0, 0, 0);
    }
    __syncthreads();
  }

  // ---- epilogue ----
  if (EPI == MG_C2) {
#pragma unroll
    for (int mt = 0; mt < 2; mt++)
#pragma unroll
      for (int r = 0; r < 16; r++) {
        int o = o0 + mt * 32 + (r & 3) + 8 * (r >> 2) + 4 * hi;
        float bv = bias[o];
        unsigned gp = p0 + wid * 32 + ln31;
        unsigned bb = gp / PIX, pp = gp - bb * PIX;
        size_t oi = ((size_t)bb * CDIM + o) * PIX + pp;
        outF[oi] = acc[mt][r] + bv + extra[oi];
      }
  } else {
    // bf16-transposed output via wave-local LDS transpose (Bs reused)
#pragma unroll
    for (int mt = 0; mt < 2; mt++)
#pragma unroll
      for (int r = 0; r < 16; r++) {
        int o_loc = mt * 32 + (r & 3) + 8 * (r >> 2) + 4 * hi;
        int o = o0 + o_loc;
        float bv = bias[o];
        int p_loc = wid * 32 + ln31;
        float val = acc[mt][r] + bv;
        if (EPI == MG_PROJ) {
          unsigned gp = p0 + p_loc;
          unsigned bb = gp / PIX, pp = gp - bb * PIX;
          size_t oi = ((size_t)bb * CDIM + o) * PIX + pp;
          val += extra[oi];
          outF[oi] = val;
        }
        if (EPI == MG_GELU)
          val = 0.5f * val * (1.f + erff(val * 0.70710678118654752f));
        *(__hip_bfloat16*)&Bs[p_loc * 64 + (((o_loc >> 3) ^ (p_loc & 7)) << 3) + (o_loc & 7)] =
            __float2bfloat16(val);
      }
    // reads stay wave-local: thread tid reads row tid>>1 (its own wave's rows)
    int prow = tid >> 1, half = tid & 1;
    int psw = prow & 7;
    uint4v r4[4];
#pragma unroll
    for (int j = 0; j < 4; j++)
      r4[j] = *(const uint4v*)&Bs[prow * 64 + ((((half << 2) + j) ^ psw) << 3)];
    unsigned gp = p0 + prow;
    if (EPI == MG_QKV) {
      unsigned bb = gp / PIX, pp = gp - bb * PIX;
      int s = o0 / 192;               // 0=q, 1=k, 2=v
      int h0 = ((o0 - s * 192) >> 5) + half;
      if (s < 2) {
        u16* d = outT + ((size_t)(bb * NHEADS + h0) * PIX + pp) * 64 + s * 32;
        *(uint4v*)(d) = r4[0]; *(uint4v*)(d + 8) = r4[1];
        *(uint4v*)(d + 16) = r4[2]; *(uint4v*)(d + 24) = r4[3];
      } else {                        // v -> vT[img][pix][32] bf16
        u16* d = outT2 + ((size_t)(bb * NHEADS + h0) * PIX + pp) * 32;
        *(uint4v*)(d) = r4[0]; *(uint4v*)(d + 8) = r4[1];
        *(uint4v*)(d + 16) = r4[2]; *(uint4v*)(d + 24) = r4[3];
      }
    } else if (EPI == MG_PROJ) {
      u16* d = outT + (size_t)gp * CDIM + o0 + half * 32;
#pragma unroll
      for (int j = 0; j < 4; j++) *(uint4v*)(d + j * 8) = r4[j];
    } else {  // GELU -> hT [gp][768]
      u16* d = outT + (size_t)gp * 768 + o0 + half * 32;
#pragma unroll
      for (int j = 0; j < 4; j++) *(uint4v*)(d + j * 8) = r4[j];
    }
  }
}

// ------ 7x7 attn conv + fused softmax/PV: granule-major patch, Ks-split -----
// 4 waves = (Nt px-half, s K-half). acc[2] = Mt. Per tap per kk: 2 A-loads +
// 1 B ds_read + 2 MFMAs. Butterfly (wid^2) merges K-halves; wave then owns
// Mt=s and writes smx rows s*32.., fused softmax + PV as before.
#define AGS 1608              // g-plane stride u16 (201*8): staggered banks
__global__ __launch_bounds__(256, 4) void attn_fused_k(
    const u16* __restrict__ qkT, const u16* __restrict__ wTb2,
    const u16* __restrict__ vT,
    const float* __restrict__ dm_b, const float* __restrict__ rel_bias,
    u16* __restrict__ attnoT) {
#define VPS 40
  __shared__ __align__(16) u16 shraw[16032];  // 32064 B
  u16* patch = shraw;                          // phase1: 8*AGS = 25728 B
  int img = blockIdx.x / 49;
  int tile = blockIdx.x % 49;
  int y0 = (tile / 7) * 8, x0 = (tile % 7) * 8;
  int tid = threadIdx.x;
  const u16* qbase = qkT + (size_t)img * PIX * 64;
  for (int idx = tid; idx < 1568; idx += 256) {
    int g = idx & 7, lp = idx >> 3;
    int r = lp / 14, c = lp - r * 14;
    int gy = y0 - 3 + r, gx = x0 - 3 + c;
    uint4v val = {0u, 0u, 0u, 0u};
    if ((unsigned)gy < 56u && (unsigned)gx < 56u)
      val = *(const uint4v*)(qbase + (size_t)(gy * 56 + gx) * 64 + g * 8);
    *(uint4v*)&patch[g * AGS + lp * 8] = val;
  }
  __syncthreads();

  int lane = tid & 63, wid = tid >> 6;
  int Nt = wid & 1, s = wid >> 1;
  int n = lane & 31, hi = lane >> 5;
  int py = Nt * 4 + (n >> 3), px = n & 7;
  f32x16 accA, accB;                    // Mt0, Mt1
#pragma unroll
  for (int i = 0; i < 16; i++) { accA[i] = 0.f; accB[i] = 0.f; }

  const u16* AbW = wTb2 + (s * 2) * 512 + lane * 8;
#pragma unroll
  for (int kh = 0; kh < 7; kh++) {
#pragma unroll
    for (int kw = 0; kw < 7; kw++) {
      int tap = kh * 7 + kw;
      int lp8 = ((py + kh) * 14 + px + kw) * 8;
      const u16* Af = AbW + tap * 2048;
#pragma unroll
      for (int kk = 0; kk < 2; kk++) {
        int g = (s * 2 + kk) * 2 + hi;
        bf16x8 a0 = __builtin_bit_cast(bf16x8, *(const uint4v*)(Af + kk * 512));
        bf16x8 a1 = __builtin_bit_cast(bf16x8, *(const uint4v*)(Af + 100352 + kk * 512));
        bf16x8 b  = __builtin_bit_cast(bf16x8, *(const uint4v*)&patch[g * AGS + lp8]);
        accA = __builtin_amdgcn_mfma_f32_32x32x16_bf16(a0, b, accA, 0, 0, 0);
        accB = __builtin_amdgcn_mfma_f32_32x32x16_bf16(a1, b, accB, 0, 0, 0);
      }
    }
  }

  // ---- butterfly: wid^2 merges K-halves; wave keeps Mt = s -----------------
  __syncthreads();
  float* rbuf = (float*)shraw;          // 4 waves x 4 quads x 64 lanes x 16B = 16 KB
#pragma unroll
  for (int q = 0; q < 4; q++) {
    float4 v4;
    if (s == 0)
      v4 = make_float4(accB[q * 4], accB[q * 4 + 1], accB[q * 4 + 2], accB[q * 4 + 3]);
    else
      v4 = make_float4(accA[q * 4], accA[q * 4 + 1], accA[q * 4 + 2], accA[q * 4 + 3]);
    *(float4*)&rbuf[(((wid * 4) + q) * 64 + lane) * 4] = v4;
  }
  __syncthreads();
  int partner = wid ^ 2;
  float fin[16];
#pragma unroll
  for (int q = 0; q < 4; q++) {
    float4 v4 = *(const float4*)&rbuf[(((partner * 4) + q) * 64 + lane) * 4];
    if (s == 0) {
      fin[q * 4] = accA[q * 4] + v4.x; fin[q * 4 + 1] = accA[q * 4 + 1] + v4.y;
      fin[q * 4 + 2] = accA[q * 4 + 2] + v4.z; fin[q * 4 + 3] = accA[q * 4 + 3] + v4.w;
    } else {
      fin[q * 4] = accB[q * 4] + v4.x; fin[q * 4 + 1] = accB[q * 4 + 1] + v4.y;
      fin[q * 4 + 2] = accB[q * 4 + 2] + v4.z; fin[q * 4 + 3] = accB[q * 4 + 3] + v4.w;
    }
  }
  __syncthreads();                      // rbuf reads done before smx overwrite

  // ---- fused tail: logits -> smx, v-patch -> vp, softmax, PV ---------------
  float* smx = (float*)shraw;           // [64 ko][64 px] fp32 (16 KB)
  u16* vp = shraw + 8192;               // [196 pix][VPS] bf16
  int head = img % NHEADS;
#pragma unroll
  for (int r = 0; r < 16; r++) {
    int ko = s * 32 + (r & 3) + 8 * (r >> 2) + 4 * hi;
    if (ko < KWIN)
      smx[ko * 64 + Nt * 32 + n] = fin[r] + dm_b[ko] + rel_bias[ko * NHEADS + head];
  }
  const u16* vbase = vT + (size_t)img * PIX * 32;
  for (int idx = tid; idx < 784; idx += 256) {
    int g = idx & 3, lp = idx >> 2;
    int r = lp / 14, c = lp - r * 14;
    int gy = y0 - 3 + r, gx = x0 - 3 + c;
    uint4v val = {0u, 0u, 0u, 0u};
    if ((unsigned)gy < 56u && (unsigned)gx < 56u)
      val = *(const uint4v*)(vbase + (size_t)(gy * 56 + gx) * 32 + g * 8);
    *(uint4v*)&vp[lp * VPS + g * 8] = val;
  }
  __syncthreads();
  if (tid < 64) {
    float a[KWIN];
    float m = -1e30f;
#pragma unroll
    for (int k = 0; k < KWIN; k++) { a[k] = smx[k * 64 + tid]; m = fmaxf(m, a[k]); }
    float sum = 0.f;
#pragma unroll
    for (int k = 0; k < KWIN; k++) { a[k] = __expf(a[k] - m); sum += a[k]; }
    float inv = 1.f / sum;
#pragma unroll
    for (int k = 0; k < KWIN; k++) smx[k * 64 + tid] = a[k] * inv;
  }
  __syncthreads();
  int pxl = tid & 63, co = tid >> 6;
  int pyy = pxl >> 3, pxx = pxl & 7;
  float o8[8] = {0.f, 0.f, 0.f, 0.f, 0.f, 0.f, 0.f, 0.f};
#pragma unroll
  for (int kh = 0; kh < 7; kh++) {
#pragma unroll
    for (int kw = 0; kw < 7; kw++) {
      float p = smx[(kh * 7 + kw) * 64 + pxl];
      bf16x8 v = *(const bf16x8*)&vp[((pyy + kh) * 14 + pxx + kw) * VPS + co * 8];
#pragma unroll
      for (int j = 0; j < 8; j++) o8[j] += p * (float)v[j];
    }
  }
  int gp = (y0 + pyy) * 56 + x0 + pxx;
  int b = img / NHEADS;
  __hip_bfloat16 ob[8];
#pragma unroll
  for (int j = 0; j < 8; j++) ob[j] = __float2bfloat16(o8[j]);
  *(uint4v*)(attnoT + ((size_t)b * PIX + gp) * CDIM + head * 32 + co * 8) = *(uint4v*)ob;
}

// ---------------- launch ----------------------------------------------------
extern "C" void kernel_launch(void* const* d_in, const int* in_sizes, int n_in,
                              void* d_out, int out_size, void* d_ws, size_t ws_size,
                              hipStream_t stream) {
  const float* x        = (const float*)d_in[0];
  const float* bn_gamma = (const float*)d_in[1];
  const float* bn_beta  = (const float*)d_in[2];
  const float* qkv_w    = (const float*)d_in[3];
  const float* qkv_b    = (const float*)d_in[4];
  const float* dm_w     = (const float*)d_in[5];
  const float* dm_b     = (const float*)d_in[6];
  const float* rel_bias = (const float*)d_in[7];
  const float* proj_w   = (const float*)d_in[8];
  const float* proj_b   = (const float*)d_in[9];
  const float* c1_w     = (const float*)d_in[10];
  const float* c1_b     = (const float*)d_in[11];
  const float* c2_w     = (const float*)d_in[12];
  const float* c2_b     = (const float*)d_in[13];
  float* out = (float*)d_out;
  float* ws  = (float*)d_ws;

  float* stats   = ws;                          // 384 f
  float* b_eff   = stats + 384;                 // 576 f
  u16*   pk_qkv  = (u16*)(b_eff + 576);         // 110592 u16
  u16*   pk_proj = pk_qkv + 110592;             // 36864
  u16*   pk_c1   = pk_proj + 36864;             // 147456
  u16*   pk_c2   = pk_c1 + 147456;              // 147456
  u16*   wTb2    = pk_c2 + 147456;              // 200704
  u16*   xT      = wTb2 + 200704;               // 2408448 u16
  u16*   qkT     = xT + 2408448;                // 4816896 u16
  u16*   vT      = qkT + 4816896;               // 2408448 u16
  u16*   attnoT  = vT + 2408448;                // 2408448 u16
  float* x1      = (float*)(attnoT + 2408448);  // 2408448 f
  u16*   x1T     = (u16*)(x1 + 2408448);        // 2408448 u16
  u16*   hT      = xT;  // alias: 9633792 u16 over dead xT+qkT+vT

  bn_stats_k<<<CDIM, 256, 0, stream>>>(x, stats);
  fold_pack_k<<<576, 192, 0, stream>>>(qkv_w, qkv_b, bn_gamma, bn_beta, stats,
                                       pk_qkv, b_eff);
  prep2_k<<<946, 256, 0, stream>>>(dm_w, wTb2, proj_w, pk_proj, c1_w, pk_c1,
                                   c2_w, pk_c2);
  xT_k<<<dim3(BATCH * 49, 6), 256, 0, stream>>>(x, xT);

  mgemm_k<MG_QKV><<<dim3(98, 9), 256, 0, stream>>>(
      xT, pk_qkv, b_eff, nullptr, qkT, vT, nullptr, 192);
  attn_fused_k<<<NIMG * 49, 256, 0, stream>>>(qkT, wTb2, vT, dm_b, rel_bias, attnoT);
  mgemm_k<MG_PROJ><<<dim3(98, 3), 256, 0, stream>>>(
      attnoT, pk_proj, proj_b, x1, x1T, nullptr, x, 192);
  mgemm_k<MG_GELU><<<dim3(98, 12), 256, 0, stream>>>(
      x1T, pk_c1, c1_b, nullptr, hT, nullptr, nullptr, 192);
  mgemm_k<MG_C2><<<dim3(98, 3), 256, 0, stream>>>(
      hT, pk_c2, c2_b, out, nullptr, nullptr, x1, 768);
}

// Round 10
// 148.754 us; speedup vs baseline: 1.2691x; 1.2691x over previous
//
#include <hip/hip_runtime.h>
#include <hip/hip_bf16.h>
#include <math.h>

#define CDIM 192
#define NHEADS 6
#define WIN 7
#define KWIN 49
#define BATCH 4
#define PIX 3136      // 56*56
#define NPIX 12544    // BATCH*PIX
#define NIMG 24       // BATCH*NHEADS
#define EPSV 1e-5f

typedef __bf16 bf16x8 __attribute__((ext_vector_type(8)));
typedef float f32x16 __attribute__((ext_vector_type(16)));
typedef unsigned int uint4v __attribute__((ext_vector_type(4)));
typedef unsigned short u16;

// ---------------- BN stats ---------------------------------------------------
__global__ __launch_bounds__(256) void bn_stats_k(const float* __restrict__ x,
                                                  float* __restrict__ stats) {
  int c = blockIdx.x;
  float s = 0.f, q = 0.f;
  for (int n = threadIdx.x; n < BATCH * PIX; n += 256) {
    int b = n / PIX, p = n - b * PIX;
    float v = x[((size_t)b * CDIM + c) * PIX + p];
    s += v; q += v * v;
  }
  __shared__ float rs[256], rq[256];
  rs[threadIdx.x] = s; rq[threadIdx.x] = q;
  __syncthreads();
  for (int st = 128; st > 0; st >>= 1) {
    if (threadIdx.x < st) { rs[threadIdx.x] += rs[threadIdx.x + st]; rq[threadIdx.x] += rq[threadIdx.x + st]; }
    __syncthreads();
  }
  if (threadIdx.x == 0) {
    float mean = rs[0] / (float)(BATCH * PIX);
    float var = rq[0] / (float)(BATCH * PIX) - mean * mean;
    stats[c] = mean;
    stats[CDIM + c] = rsqrtf(var + EPSV);
  }
}

// ------- fold BN + q-scale into qkv weights, writing PACKED frags directly --
__global__ __launch_bounds__(192) void fold_pack_k(
    const float* __restrict__ qkv_w, const float* __restrict__ qkv_b,
    const float* __restrict__ gamma, const float* __restrict__ beta,
    const float* __restrict__ stats, u16* __restrict__ pk_qkv,
    float* __restrict__ b_eff) {
  int o = blockIdx.x, c = threadIdx.x;
  float alpha = gamma[c] * stats[CDIM + c];
  float shift = beta[c] - stats[c] * alpha;
  float w = qkv_w[o * CDIM + c];
  float scale = (o < CDIM) ? 0.17677669529663687f : 1.f;
  int t8 = ((((o >> 5) * 12 + (c >> 4)) * 64 + (((c >> 3) & 1) * 32 + (o & 31))) << 3) + (c & 7);
  ((__hip_bfloat16*)pk_qkv)[t8] = __float2bfloat16(w * alpha * scale);
  __shared__ float r[CDIM];
  r[c] = w * shift;
  __syncthreads();
  if (c == 0) {
    float s = 0.f;
    for (int i = 0; i < CDIM; i++) s += r[i];
    b_eff[o] = (qkv_b[o] + s) * scale;
  }
}

// ---------------- generic pack helper: W[Cout][Cin] -> frag-major -----------
__device__ inline void pack_one(const float* __restrict__ W, u16* __restrict__ out,
                                int Cin, int t) {
  int lane = t & 63, rest = t >> 6;
  int nK = Cin >> 4;
  int kk = rest % nK, mtg = rest / nK;
  int o = mtg * 32 + (lane & 31), c = kk * 16 + (lane >> 5) * 8;
  const float* src = W + (size_t)o * Cin + c;
  __hip_bfloat16 tmp[8];
#pragma unroll
  for (int e = 0; e < 8; e++) tmp[e] = __float2bfloat16(src[e]);
  *(uint4v*)(out + (size_t)t * 8) = *(uint4v*)tmp;
}

// --- merged prep: dm_w pack + proj/c1/c2 packs + xT transpose (one launch) --
__global__ __launch_bounds__(256) void prep3_k(
    const float* __restrict__ dm_w, u16* __restrict__ wTb2,
    const float* __restrict__ proj_w, u16* __restrict__ pk_proj,
    const float* __restrict__ c1_w, u16* __restrict__ pk_c1,
    const float* __restrict__ c2_w, u16* __restrict__ pk_c2,
    const float* __restrict__ x, u16* __restrict__ xT) {
  __shared__ float Ls[64][33];
  int bid = blockIdx.x, tid = threadIdx.x;
  if (bid < 784) {
    int idx = bid * 256 + tid;
    int e = idx & 7;
    int tmp = idx >> 3;
    int lane = tmp & 63; tmp >>= 6;
    int ch = tmp & 3; tmp >>= 2;
    int tap = tmp % 49, Mt = tmp / 49;
    int ko = Mt * 32 + (lane & 31);
    int ci = ch * 16 + (lane >> 5) * 8 + e;
    float v = (ko < KWIN) ? dm_w[(size_t)ko * 3136 + ci * 49 + tap] : 0.f;
    ((__hip_bfloat16*)wTb2)[idx] = __float2bfloat16(v);
  } else if (bid < 802) {
    int t = (bid - 784) * 256 + tid;
    if (t < 4608) pack_one(proj_w, pk_proj, 192, t);
  } else if (bid < 874) {
    int t = (bid - 802) * 256 + tid;
    if (t < 18432) pack_one(c1_w, pk_c1, 192, t);
  } else if (bid < 946) {
    int t = (bid - 874) * 256 + tid;
    if (t < 18432) pack_one(c2_w, pk_c2, 768, t);
  } else {
    int t = bid - 946;                 // [0,1176): xT transpose
    int bx = t % 196, by = t / 196;
    int bb = bx / 49;
    int p0 = (bx % 49) * 64;
    int c0 = by * 32;
    int j = tid & 63;
#pragma unroll
    for (int it = 0; it < 8; it++) {
      int c = it * 4 + (tid >> 6);
      Ls[j][c] = x[((size_t)bb * CDIM + c0 + c) * PIX + p0 + j];
    }
    __syncthreads();
    int jr = tid >> 2, tt = tid & 3;
    __hip_bfloat16 tmp[8];
#pragma unroll
    for (int u = 0; u < 8; u++) tmp[u] = __float2bfloat16(Ls[jr][tt * 8 + u]);
    *(uint4v*)(xT + (size_t)(bb * PIX + p0 + jr) * CDIM + c0 + tt * 8) = *(uint4v*)tmp;
  }
}

// ---------------- MFMA GEMM (round-8 256px tile + A staged in LDS) ----------
#define MG_QKV 0
#define MG_PROJ 1
#define MG_GELU 2
#define MG_C2 3
#define MGS 2056

template <int EPI>
__global__ __launch_bounds__(256, 3) void mgemm_k(
    const u16* __restrict__ Bm, const u16* __restrict__ Apk,
    const float* __restrict__ bias,
    float* __restrict__ outF, u16* __restrict__ outT, u16* __restrict__ outT2,
    const float* __restrict__ extra, int Cin) {
  __shared__ __align__(16) u16 Bs[8 * MGS];  // 32.9 KB
  __shared__ __align__(16) u16 As[4096];     // 8 KB: [mt(2)][ks(4)] frags
  int tid = threadIdx.x;
  int lane = tid & 63, wid = tid >> 6;
  int hi = lane >> 5, ln31 = lane & 31;
  int p0 = blockIdx.x * 256;
  int o0 = blockIdx.y * 64;
  int nK = Cin >> 4;
  f32x16 acc[2][2];
#pragma unroll
  for (int mt = 0; mt < 2; mt++)
#pragma unroll
    for (int nt = 0; nt < 2; nt++)
#pragma unroll
      for (int i = 0; i < 16; i++) acc[mt][nt][i] = 0.f;

  for (int cc = 0; cc < Cin; cc += 64) {
#pragma unroll
    for (int i = 0; i < 8; i++) {
      int idx = i * 256 + tid;
      int g = idx & 7, p = idx >> 3;
      uint4v v = *(const uint4v*)(Bm + (size_t)(p0 + p) * Cin + cc + g * 8);
      *(uint4v*)&Bs[g * MGS + p * 8] = v;
    }
    // stage A chunk once per block (each wave 1/4): 8 frags x 512 u16
#pragma unroll
    for (int i = 0; i < 2; i++) {
      int idx = i * 256 + tid;            // [0,512)
      int frag = idx >> 6, l64 = idx & 63;
      int mt = frag >> 2, ks = frag & 3;
      uint4v v = *(const uint4v*)(Apk +
          (size_t)(((o0 >> 5) + mt) * nK + (cc >> 4) + ks) * 512 + l64 * 8);
      *(uint4v*)&As[frag * 512 + l64 * 8] = v;
    }
    __syncthreads();
    int pA = wid * 64 + ln31;
    int pB = pA + 32;
#pragma unroll
    for (int ks = 0; ks < 4; ks++) {
      int g = ks * 2 + hi;
      bf16x8 b0 = *(const bf16x8*)&Bs[g * MGS + pA * 8];
      bf16x8 b1 = *(const bf16x8*)&Bs[g * MGS + pB * 8];
      bf16x8 a0 = *(const bf16x8*)&As[ks * 512 + lane * 8];
      bf16x8 a1 = *(const bf16x8*)&As[(4 + ks) * 512 + lane * 8];
      acc[0][0] = __builtin_amdgcn_mfma_f32_32x32x16_bf16(a0, b0, acc[0][0], 0, 0, 0);
      acc[0][1] = __builtin_amdgcn_mfma_f32_32x32x16_bf16(a0, b1, acc[0][1], 0, 0, 0);
      acc[1][0] = __builtin_amdgcn_mfma_f32_32x32x16_bf16(a1, b0, acc[1][0], 0, 0, 0);
      acc[1][1] = __builtin_amdgcn_mfma_f32_32x32x16_bf16(a1, b1, acc[1][1], 0, 0, 0);
    }
    __syncthreads();
  }

  // ---- epilogue (round-8) ----
  if (EPI == MG_C2) {
#pragma unroll
    for (int mt = 0; mt < 2; mt++)
#pragma unroll
      for (int r = 0; r < 16; r++) {
        int o = o0 + mt * 32 + (r & 3) + 8 * (r >> 2) + 4 * hi;
        float bv = bias[o];
#pragma unroll
        for (int nt = 0; nt < 2; nt++) {
          unsigned gp = p0 + wid * 64 + nt * 32 + ln31;
          unsigned bb = gp / PIX, pp = gp - bb * PIX;
          size_t oi = ((size_t)bb * CDIM + o) * PIX + pp;
          outF[oi] = acc[mt][nt][r] + bv + extra[oi];
        }
      }
  } else {
#pragma unroll
    for (int mt = 0; mt < 2; mt++)
#pragma unroll
      for (int r = 0; r < 16; r++) {
        int o_loc = mt * 32 + (r & 3) + 8 * (r >> 2) + 4 * hi;
        int o = o0 + o_loc;
        float bv = bias[o];
#pragma unroll
        for (int nt = 0; nt < 2; nt++) {
          int p_loc = wid * 64 + nt * 32 + ln31;
          float val = acc[mt][nt][r] + bv;
          if (EPI == MG_PROJ) {
            unsigned gp = p0 + p_loc;
            unsigned bb = gp / PIX, pp = gp - bb * PIX;
            size_t oi = ((size_t)bb * CDIM + o) * PIX + pp;
            val += extra[oi];
            outF[oi] = val;
          }
          if (EPI == MG_GELU)
            val = 0.5f * val * (1.f + erff(val * 0.70710678118654752f));
          *(__hip_bfloat16*)&Bs[p_loc * 64 + (((o_loc >> 3) ^ (p_loc & 7)) << 3) + (o_loc & 7)] =
              __float2bfloat16(val);
        }
      }
    __syncthreads();
    int prow = wid * 64 + lane;
    int psw = prow & 7;
    uint4v r8[8];
#pragma unroll
    for (int g = 0; g < 8; g++)
      r8[g] = *(const uint4v*)&Bs[prow * 64 + ((g ^ psw) << 3)];
    unsigned gp = p0 + prow;
    if (EPI == MG_QKV) {
      unsigned bb = gp / PIX, pp = gp - bb * PIX;
      int s = o0 / 192;               // 0=q, 1=k, 2=v
      int rr = o0 - s * 192;
      int h0 = rr >> 5;
      if (s < 2) {
        u16* d0 = outT + ((size_t)(bb * NHEADS + h0) * PIX + pp) * 64 + s * 32;
        u16* d1 = outT + ((size_t)(bb * NHEADS + h0 + 1) * PIX + pp) * 64 + s * 32;
        *(uint4v*)(d0) = r8[0]; *(uint4v*)(d0 + 8) = r8[1];
        *(uint4v*)(d0 + 16) = r8[2]; *(uint4v*)(d0 + 24) = r8[3];
        *(uint4v*)(d1) = r8[4]; *(uint4v*)(d1 + 8) = r8[5];
        *(uint4v*)(d1 + 16) = r8[6]; *(uint4v*)(d1 + 24) = r8[7];
      } else {                        // v -> vT[img][pix][32] bf16
        u16* d0 = outT2 + ((size_t)(bb * NHEADS + h0) * PIX + pp) * 32;
        u16* d1 = outT2 + ((size_t)(bb * NHEADS + h0 + 1) * PIX + pp) * 32;
        *(uint4v*)(d0) = r8[0]; *(uint4v*)(d0 + 8) = r8[1];
        *(uint4v*)(d0 + 16) = r8[2]; *(uint4v*)(d0 + 24) = r8[3];
        *(uint4v*)(d1) = r8[4]; *(uint4v*)(d1 + 8) = r8[5];
        *(uint4v*)(d1 + 16) = r8[6]; *(uint4v*)(d1 + 24) = r8[7];
      }
    } else if (EPI == MG_PROJ) {
      u16* d = outT + (size_t)gp * CDIM + o0;
#pragma unroll
      for (int g = 0; g < 8; g++) *(uint4v*)(d + g * 8) = r8[g];
    } else {  // GELU -> hT [gp][768]
      u16* d = outT + (size_t)gp * 768 + o0;
#pragma unroll
      for (int g = 0; g < 8; g++) *(uint4v*)(d + g * 8) = r8[g];
    }
  }
}

// ------ 7x7 attn conv (round-8 core + A-prefetch) + fused softmax/PV --------
#define VPS 40
__global__ __launch_bounds__(256, 4) void attn_fused_k(
    const u16* __restrict__ qkT, const u16* __restrict__ wTb2,
    const u16* __restrict__ vT,
    const float* __restrict__ dm_b, const float* __restrict__ rel_bias,
    u16* __restrict__ attnoT) {
  __shared__ __align__(16) u16 shraw[16032];
  u16* patch = shraw;
  int img = blockIdx.x / 49;
  int tile = blockIdx.x % 49;
  int y0 = (tile / 7) * 8, x0 = (tile % 7) * 8;
  int tid = threadIdx.x;
  const u16* qbase = qkT + (size_t)img * PIX * 64;
  for (int idx = tid; idx < 1568; idx += 256) {
    int pix = idx >> 3, g = idx & 7;
    int r = pix / 14, c = pix - r * 14;
    int gy = y0 - 3 + r, gx = x0 - 3 + c;
    uint4v val = {0u, 0u, 0u, 0u};
    if ((unsigned)gy < 56u && (unsigned)gx < 56u)
      val = *(const uint4v*)(qbase + (size_t)(gy * 56 + gx) * 64 + g * 8);
    *(uint4v*)&patch[pix * 64 + ((g ^ (pix & 7)) << 3)] = val;
  }
  __syncthreads();

  int lane = tid & 63, wid = tid >> 6;
  int Mtile = wid & 1, Ntile = wid >> 1;
  int n = lane & 31, kgrp = lane >> 5;
  int py = Ntile * 4 + (n >> 3), px = n & 7;
  f32x16 acc;
#pragma unroll
  for (int i = 0; i < 16; i++) acc[i] = 0.f;

  const u16* Abase = wTb2 + (size_t)Mtile * 100352 + lane * 8;
  // 1-tap-ahead register prefetch of the 4 A-fragments
  bf16x8 aP[4];
#pragma unroll
  for (int ch = 0; ch < 4; ch++)
    aP[ch] = __builtin_bit_cast(bf16x8, *(const uint4v*)(Abase + ch * 512));
#pragma unroll
  for (int kh = 0; kh < 7; kh++) {
#pragma unroll
    for (int kw = 0; kw < 7; kw++) {
      int tap = kh * 7 + kw;
      int lp = (py + kh) * 14 + px + kw;
      int lpand = lp & 7;
      bf16x8 aC[4];
#pragma unroll
      for (int ch = 0; ch < 4; ch++) aC[ch] = aP[ch];
      int ntap = (tap < 48) ? tap + 1 : 48;
      const u16* An = Abase + (size_t)(ntap * 4) * 512;
#pragma unroll
      for (int ch = 0; ch < 4; ch++)
        aP[ch] = __builtin_bit_cast(bf16x8, *(const uint4v*)(An + ch * 512));
#pragma unroll
      for (int ch = 0; ch < 4; ch++) {
        int g = ch * 2 + kgrp;
        bf16x8 bb = __builtin_bit_cast(bf16x8,
            *(const uint4v*)&patch[lp * 64 + ((g ^ lpand) << 3)]);
        acc = __builtin_amdgcn_mfma_f32_32x32x16_bf16(aC[ch], bb, acc, 0, 0, 0);
      }
    }
  }

  // ---- fused tail: logits -> LDS, v-patch -> LDS, softmax, PV --------------
  __syncthreads();
  float* smx = (float*)shraw;            // [64 ko][64 px] fp32
  u16* vp = shraw + 8192;                // [196 pix][VPS] bf16
  int head = img % NHEADS;
#pragma unroll
  for (int r = 0; r < 16; r++) {
    int ko = Mtile * 32 + (r & 3) + 8 * (r >> 2) + 4 * kgrp;
    if (ko < KWIN)
      smx[ko * 64 + Ntile * 32 + n] = acc[r] + dm_b[ko] + rel_bias[ko * NHEADS + head];
  }
  const u16* vbase = vT + (size_t)img * PIX * 32;
  for (int idx = tid; idx < 784; idx += 256) {
    int g = idx & 3, lp = idx >> 2;
    int r = lp / 14, c = lp - r * 14;
    int gy = y0 - 3 + r, gx = x0 - 3 + c;
    uint4v val = {0u, 0u, 0u, 0u};
    if ((unsigned)gy < 56u && (unsigned)gx < 56u)
      val = *(const uint4v*)(vbase + (size_t)(gy * 56 + gx) * 32 + g * 8);
    *(uint4v*)&vp[lp * VPS + g * 8] = val;
  }
  __syncthreads();
  if (tid < 64) {
    float a[KWIN];
    float m = -1e30f;
#pragma unroll
    for (int k = 0; k < KWIN; k++) { a[k] = smx[k * 64 + tid]; m = fmaxf(m, a[k]); }
    float s = 0.f;
#pragma unroll
    for (int k = 0; k < KWIN; k++) { a[k] = __expf(a[k] - m); s += a[k]; }
    float inv = 1.f / s;
#pragma unroll
    for (int k = 0; k < KWIN; k++) smx[k * 64 + tid] = a[k] * inv;
  }
  __syncthreads();
  int pxl = tid & 63, co = tid >> 6;
  int pyy = pxl >> 3, pxx = pxl & 7;
  float o8[8] = {0.f, 0.f, 0.f, 0.f, 0.f, 0.f, 0.f, 0.f};
#pragma unroll
  for (int kh = 0; kh < 7; kh++) {
#pragma unroll
    for (int kw = 0; kw < 7; kw++) {
      float p = smx[(kh * 7 + kw) * 64 + pxl];
      bf16x8 v = *(const bf16x8*)&vp[((pyy + kh) * 14 + pxx + kw) * VPS + co * 8];
#pragma unroll
      for (int j = 0; j < 8; j++) o8[j] += p * (float)v[j];
    }
  }
  int gp = (y0 + pyy) * 56 + x0 + pxx;
  int b = img / NHEADS;
  __hip_bfloat16 ob[8];
#pragma unroll
  for (int j = 0; j < 8; j++) ob[j] = __float2bfloat16(o8[j]);
  *(uint4v*)(attnoT + ((size_t)b * PIX + gp) * CDIM + head * 32 + co * 8) = *(uint4v*)ob;
}

// ---------------- launch ----------------------------------------------------
extern "C" void kernel_launch(void* const* d_in, const int* in_sizes, int n_in,
                              void* d_out, int out_size, void* d_ws, size_t ws_size,
                              hipStream_t stream) {
  const float* x        = (const float*)d_in[0];
  const float* bn_gamma = (const float*)d_in[1];
  const float* bn_beta  = (const float*)d_in[2];
  const float* qkv_w    = (const float*)d_in[3];
  const float* qkv_b    = (const float*)d_in[4];
  const float* dm_w     = (const float*)d_in[5];
  const float* dm_b     = (const float*)d_in[6];
  const float* rel_bias = (const float*)d_in[7];
  const float* proj_w   = (const float*)d_in[8];
  const float* proj_b   = (const float*)d_in[9];
  const float* c1_w     = (const float*)d_in[10];
  const float* c1_b     = (const float*)d_in[11];
  const float* c2_w     = (const float*)d_in[12];
  const float* c2_b     = (const float*)d_in[13];
  float* out = (float*)d_out;
  float* ws  = (float*)d_ws;

  float* stats   = ws;                          // 384 f
  float* b_eff   = stats + 384;                 // 576 f
  u16*   pk_qkv  = (u16*)(b_eff + 576);         // 110592 u16
  u16*   pk_proj = pk_qkv + 110592;             // 36864
  u16*   pk_c1   = pk_proj + 36864;             // 147456
  u16*   pk_c2   = pk_c1 + 147456;              // 147456
  u16*   wTb2    = pk_c2 + 147456;              // 200704
  u16*   xT      = wTb2 + 200704;               // 2408448 u16
  u16*   qkT     = xT + 2408448;                // 4816896 u16
  u16*   vT      = qkT + 4816896;               // 2408448 u16
  u16*   attnoT  = vT + 2408448;                // 2408448 u16
  float* x1      = (float*)(attnoT + 2408448);  // 2408448 f
  u16*   x1T     = (u16*)(x1 + 2408448);        // 2408448 u16
  u16*   hT      = xT;  // alias: 9633792 u16 over dead xT+qkT+vT

  bn_stats_k<<<CDIM, 256, 0, stream>>>(x, stats);
  prep3_k<<<2122, 256, 0, stream>>>(dm_w, wTb2, proj_w, pk_proj, c1_w, pk_c1,
                                    c2_w, pk_c2, x, xT);
  fold_pack_k<<<576, 192, 0, stream>>>(qkv_w, qkv_b, bn_gamma, bn_beta, stats,
                                       pk_qkv, b_eff);

  mgemm_k<MG_QKV><<<dim3(49, 9), 256, 0, stream>>>(
      xT, pk_qkv, b_eff, nullptr, qkT, vT, nullptr, 192);
  attn_fused_k<<<NIMG * 49, 256, 0, stream>>>(qkT, wTb2, vT, dm_b, rel_bias, attnoT);
  mgemm_k<MG_PROJ><<<dim3(49, 3), 256, 0, stream>>>(
      attnoT, pk_proj, proj_b, x1, x1T, nullptr, x, 192);
  mgemm_k<MG_GELU><<<dim3(49, 12), 256, 0, stream>>>(
      x1T, pk_c1, c1_b, nullptr, hT, nullptr, nullptr, 192);
  mgemm_k<MG_C2><<<dim3(49, 3), 256, 0, stream>>>(
      hT, pk_c2, c2_b, out, nullptr, nullptr, x1, 768);
}

// Round 11
// 146.029 us; speedup vs baseline: 1.2928x; 1.0187x over previous
//
#include <hip/hip_runtime.h>
#include <hip/hip_bf16.h>
#include <math.h>

#define CDIM 192
#define NHEADS 6
#define WIN 7
#define KWIN 49
#define BATCH 4
#define PIX 3136      // 56*56
#define NPIX 12544    // BATCH*PIX
#define NIMG 24       // BATCH*NHEADS
#define EPSV 1e-5f

typedef __bf16 bf16x8 __attribute__((ext_vector_type(8)));
typedef float f32x16 __attribute__((ext_vector_type(16)));
typedef unsigned int uint4v __attribute__((ext_vector_type(4)));
typedef unsigned int uint2v __attribute__((ext_vector_type(2)));
typedef unsigned short u16;
typedef unsigned char u8;

__device__ inline u8 f32_to_fp8(float v) {
  return (u8)(__builtin_amdgcn_cvt_pk_fp8_f32(v, 0.f, 0, false) & 0xFF);
}

// ---------------- BN stats ---------------------------------------------------
__global__ __launch_bounds__(256) void bn_stats_k(const float* __restrict__ x,
                                                  float* __restrict__ stats) {
  int c = blockIdx.x;
  float s = 0.f, q = 0.f;
  for (int n = threadIdx.x; n < BATCH * PIX; n += 256) {
    int b = n / PIX, p = n - b * PIX;
    float v = x[((size_t)b * CDIM + c) * PIX + p];
    s += v; q += v * v;
  }
  __shared__ float rs[256], rq[256];
  rs[threadIdx.x] = s; rq[threadIdx.x] = q;
  __syncthreads();
  for (int st = 128; st > 0; st >>= 1) {
    if (threadIdx.x < st) { rs[threadIdx.x] += rs[threadIdx.x + st]; rq[threadIdx.x] += rq[threadIdx.x + st]; }
    __syncthreads();
  }
  if (threadIdx.x == 0) {
    float mean = rs[0] / (float)(BATCH * PIX);
    float var = rq[0] / (float)(BATCH * PIX) - mean * mean;
    stats[c] = mean;
    stats[CDIM + c] = rsqrtf(var + EPSV);
  }
}

// ------- fold BN + q-scale into qkv weights, writing PACKED frags directly --
__global__ __launch_bounds__(192) void fold_pack_k(
    const float* __restrict__ qkv_w, const float* __restrict__ qkv_b,
    const float* __restrict__ gamma, const float* __restrict__ beta,
    const float* __restrict__ stats, u16* __restrict__ pk_qkv,
    float* __restrict__ b_eff) {
  int o = blockIdx.x, c = threadIdx.x;
  float alpha = gamma[c] * stats[CDIM + c];
  float shift = beta[c] - stats[c] * alpha;
  float w = qkv_w[o * CDIM + c];
  float scale = (o < CDIM) ? 0.17677669529663687f : 1.f;
  int t8 = ((((o >> 5) * 12 + (c >> 4)) * 64 + (((c >> 3) & 1) * 32 + (o & 31))) << 3) + (c & 7);
  ((__hip_bfloat16*)pk_qkv)[t8] = __float2bfloat16(w * alpha * scale);
  __shared__ float r[CDIM];
  r[c] = w * shift;
  __syncthreads();
  if (c == 0) {
    float s = 0.f;
    for (int i = 0; i < CDIM; i++) s += r[i];
    b_eff[o] = (qkv_b[o] + s) * scale;
  }
}

// ---------------- generic pack helper: W[Cout][Cin] -> frag-major -----------
__device__ inline void pack_one(const float* __restrict__ W, u16* __restrict__ out,
                                int Cin, int t) {
  int lane = t & 63, rest = t >> 6;
  int nK = Cin >> 4;
  int kk = rest % nK, mtg = rest / nK;
  int o = mtg * 32 + (lane & 31), c = kk * 16 + (lane >> 5) * 8;
  const float* src = W + (size_t)o * Cin + c;
  __hip_bfloat16 tmp[8];
#pragma unroll
  for (int e = 0; e < 8; e++) tmp[e] = __float2bfloat16(src[e]);
  *(uint4v*)(out + (size_t)t * 8) = *(uint4v*)tmp;
}

// --- merged prep: dm_w FP8 pack + proj/c1/c2 packs + xT transpose -----------
__global__ __launch_bounds__(256) void prep3_k(
    const float* __restrict__ dm_w, u8* __restrict__ wTb8,
    const float* __restrict__ proj_w, u16* __restrict__ pk_proj,
    const float* __restrict__ c1_w, u16* __restrict__ pk_c1,
    const float* __restrict__ c2_w, u16* __restrict__ pk_c2,
    const float* __restrict__ x, u16* __restrict__ xT) {
  __shared__ float Ls[64][33];
  int bid = blockIdx.x, tid = threadIdx.x;
  if (bid < 784) {
    int idx = bid * 256 + tid;
    int e = idx & 7;
    int tmp = idx >> 3;
    int lane = tmp & 63; tmp >>= 6;
    int ch = tmp & 3; tmp >>= 2;
    int tap = tmp % 49, Mt = tmp / 49;
    int ko = Mt * 32 + (lane & 31);
    int ci = ch * 16 + (lane >> 5) * 8 + e;
    float v = (ko < KWIN) ? dm_w[(size_t)ko * 3136 + ci * 49 + tap] : 0.f;
    wTb8[idx] = f32_to_fp8(v);
  } else if (bid < 802) {
    int t = (bid - 784) * 256 + tid;
    if (t < 4608) pack_one(proj_w, pk_proj, 192, t);
  } else if (bid < 874) {
    int t = (bid - 802) * 256 + tid;
    if (t < 18432) pack_one(c1_w, pk_c1, 192, t);
  } else if (bid < 946) {
    int t = (bid - 874) * 256 + tid;
    if (t < 18432) pack_one(c2_w, pk_c2, 768, t);
  } else {
    int t = bid - 946;                 // [0,1176): xT transpose
    int bx = t % 196, by = t / 196;
    int bb = bx / 49;
    int p0 = (bx % 49) * 64;
    int c0 = by * 32;
    int j = tid & 63;
#pragma unroll
    for (int it = 0; it < 8; it++) {
      int c = it * 4 + (tid >> 6);
      Ls[j][c] = x[((size_t)bb * CDIM + c0 + c) * PIX + p0 + j];
    }
    __syncthreads();
    int jr = tid >> 2, tt = tid & 3;
    __hip_bfloat16 tmp[8];
#pragma unroll
    for (int u = 0; u < 8; u++) tmp[u] = __float2bfloat16(Ls[jr][tt * 8 + u]);
    *(uint4v*)(xT + (size_t)(bb * PIX + p0 + jr) * CDIM + c0 + tt * 8) = *(uint4v*)tmp;
  }
}

// ---------------- MFMA GEMM (256px tile + A staged in LDS) ------------------
#define MG_QKV 0
#define MG_PROJ 1
#define MG_GELU 2
#define MG_C2 3
#define MGS 2056

template <int EPI>
__global__ __launch_bounds__(256, 3) void mgemm_k(
    const u16* __restrict__ Bm, const u16* __restrict__ Apk,
    const float* __restrict__ bias,
    float* __restrict__ outF, u16* __restrict__ outT, u16* __restrict__ outT2,
    const float* __restrict__ extra, int Cin) {
  __shared__ __align__(16) u16 Bs[8 * MGS];  // 32.9 KB
  __shared__ __align__(16) u16 As[4096];     // 8 KB
  int tid = threadIdx.x;
  int lane = tid & 63, wid = tid >> 6;
  int hi = lane >> 5, ln31 = lane & 31;
  int p0 = blockIdx.x * 256;
  int o0 = blockIdx.y * 64;
  int nK = Cin >> 4;
  f32x16 acc[2][2];
#pragma unroll
  for (int mt = 0; mt < 2; mt++)
#pragma unroll
    for (int nt = 0; nt < 2; nt++)
#pragma unroll
      for (int i = 0; i < 16; i++) acc[mt][nt][i] = 0.f;

  for (int cc = 0; cc < Cin; cc += 64) {
#pragma unroll
    for (int i = 0; i < 8; i++) {
      int idx = i * 256 + tid;
      int g = idx & 7, p = idx >> 3;
      uint4v v = *(const uint4v*)(Bm + (size_t)(p0 + p) * Cin + cc + g * 8);
      *(uint4v*)&Bs[g * MGS + p * 8] = v;
    }
#pragma unroll
    for (int i = 0; i < 2; i++) {
      int idx = i * 256 + tid;
      int frag = idx >> 6, l64 = idx & 63;
      int mt = frag >> 2, ks = frag & 3;
      uint4v v = *(const uint4v*)(Apk +
          (size_t)(((o0 >> 5) + mt) * nK + (cc >> 4) + ks) * 512 + l64 * 8);
      *(uint4v*)&As[frag * 512 + l64 * 8] = v;
    }
    __syncthreads();
    int pA = wid * 64 + ln31;
    int pB = pA + 32;
#pragma unroll
    for (int ks = 0; ks < 4; ks++) {
      int g = ks * 2 + hi;
      bf16x8 b0 = *(const bf16x8*)&Bs[g * MGS + pA * 8];
      bf16x8 b1 = *(const bf16x8*)&Bs[g * MGS + pB * 8];
      bf16x8 a0 = *(const bf16x8*)&As[ks * 512 + lane * 8];
      bf16x8 a1 = *(const bf16x8*)&As[(4 + ks) * 512 + lane * 8];
      acc[0][0] = __builtin_amdgcn_mfma_f32_32x32x16_bf16(a0, b0, acc[0][0], 0, 0, 0);
      acc[0][1] = __builtin_amdgcn_mfma_f32_32x32x16_bf16(a0, b1, acc[0][1], 0, 0, 0);
      acc[1][0] = __builtin_amdgcn_mfma_f32_32x32x16_bf16(a1, b0, acc[1][0], 0, 0, 0);
      acc[1][1] = __builtin_amdgcn_mfma_f32_32x32x16_bf16(a1, b1, acc[1][1], 0, 0, 0);
    }
    __syncthreads();
  }

  // ---- epilogue ----
  if (EPI == MG_C2) {
#pragma unroll
    for (int mt = 0; mt < 2; mt++)
#pragma unroll
      for (int r = 0; r < 16; r++) {
        int o = o0 + mt * 32 + (r & 3) + 8 * (r >> 2) + 4 * hi;
        float bv = bias[o];
#pragma unroll
        for (int nt = 0; nt < 2; nt++) {
          unsigned gp = p0 + wid * 64 + nt * 32 + ln31;
          unsigned bb = gp / PIX, pp = gp - bb * PIX;
          size_t oi = ((size_t)bb * CDIM + o) * PIX + pp;
          outF[oi] = acc[mt][nt][r] + bv + extra[oi];
        }
      }
  } else {
#pragma unroll
    for (int mt = 0; mt < 2; mt++)
#pragma unroll
      for (int r = 0; r < 16; r++) {
        int o_loc = mt * 32 + (r & 3) + 8 * (r >> 2) + 4 * hi;
        int o = o0 + o_loc;
        float bv = bias[o];
#pragma unroll
        for (int nt = 0; nt < 2; nt++) {
          int p_loc = wid * 64 + nt * 32 + ln31;
          float val = acc[mt][nt][r] + bv;
          if (EPI == MG_PROJ) {
            unsigned gp = p0 + p_loc;
            unsigned bb = gp / PIX, pp = gp - bb * PIX;
            size_t oi = ((size_t)bb * CDIM + o) * PIX + pp;
            val += extra[oi];
            outF[oi] = val;
          }
          if (EPI == MG_GELU)
            val = 0.5f * val * (1.f + erff(val * 0.70710678118654752f));
          *(__hip_bfloat16*)&Bs[p_loc * 64 + (((o_loc >> 3) ^ (p_loc & 7)) << 3) + (o_loc & 7)] =
              __float2bfloat16(val);
        }
      }
    __syncthreads();
    int prow = wid * 64 + lane;
    int psw = prow & 7;
    uint4v r8[8];
#pragma unroll
    for (int g = 0; g < 8; g++)
      r8[g] = *(const uint4v*)&Bs[prow * 64 + ((g ^ psw) << 3)];
    unsigned gp = p0 + prow;
    if (EPI == MG_QKV) {
      unsigned bb = gp / PIX, pp = gp - bb * PIX;
      int s = o0 / 192;               // 0=q, 1=k, 2=v
      int rr = o0 - s * 192;
      int h0 = rr >> 5;
      if (s < 2) {
        u16* d0 = outT + ((size_t)(bb * NHEADS + h0) * PIX + pp) * 64 + s * 32;
        u16* d1 = outT + ((size_t)(bb * NHEADS + h0 + 1) * PIX + pp) * 64 + s * 32;
        *(uint4v*)(d0) = r8[0]; *(uint4v*)(d0 + 8) = r8[1];
        *(uint4v*)(d0 + 16) = r8[2]; *(uint4v*)(d0 + 24) = r8[3];
        *(uint4v*)(d1) = r8[4]; *(uint4v*)(d1 + 8) = r8[5];
        *(uint4v*)(d1 + 16) = r8[6]; *(uint4v*)(d1 + 24) = r8[7];
      } else {                        // v -> vT[img][pix][32] bf16
        u16* d0 = outT2 + ((size_t)(bb * NHEADS + h0) * PIX + pp) * 32;
        u16* d1 = outT2 + ((size_t)(bb * NHEADS + h0 + 1) * PIX + pp) * 32;
        *(uint4v*)(d0) = r8[0]; *(uint4v*)(d0 + 8) = r8[1];
        *(uint4v*)(d0 + 16) = r8[2]; *(uint4v*)(d0 + 24) = r8[3];
        *(uint4v*)(d1) = r8[4]; *(uint4v*)(d1 + 8) = r8[5];
        *(uint4v*)(d1 + 16) = r8[6]; *(uint4v*)(d1 + 24) = r8[7];
      }
    } else if (EPI == MG_PROJ) {
      u16* d = outT + (size_t)gp * CDIM + o0;
#pragma unroll
      for (int g = 0; g < 8; g++) *(uint4v*)(d + g * 8) = r8[g];
    } else {  // GELU -> hT [gp][768]
      u16* d = outT + (size_t)gp * 768 + o0;
#pragma unroll
      for (int g = 0; g < 8; g++) *(uint4v*)(d + g * 8) = r8[g];
    }
  }
}

// ------ 7x7 attn conv (FP8 MFMA) + fused softmax/PV -------------------------
// Patch staged as fp8 (bf16->fp8 cvt during staging), granule-major planes of
// 8 ci, plane stride 1576B. A (weights) pre-packed fp8: frags 512B. Per
// (tap,ch): 8B A-load + 8B B ds_read + 1 MFMA fp8 (K=16). Halves L2 A-traffic
// and LDS B bytes vs bf16 at identical MFMA count/rate.
#define APL 1576   // fp8 patch plane stride (bytes)
#define VPS 40
__global__ __launch_bounds__(256, 4) void attn_fused_k(
    const u16* __restrict__ qkT, const u8* __restrict__ wTb8,
    const u16* __restrict__ vT,
    const float* __restrict__ dm_b, const float* __restrict__ rel_bias,
    u16* __restrict__ attnoT) {
  __shared__ __align__(16) u16 shraw[16032];
  u8* patchB = (u8*)shraw;               // phase1: 8 planes x 1576B = 12.6 KB
  int img = blockIdx.x / 49;
  int tile = blockIdx.x % 49;
  int y0 = (tile / 7) * 8, x0 = (tile % 7) * 8;
  int tid = threadIdx.x;
  const u16* qbase = qkT + (size_t)img * PIX * 64;
  for (int idx = tid; idx < 1568; idx += 256) {
    int lp = idx >> 3, g = idx & 7;
    int r = lp / 14, c = lp - r * 14;
    int gy = y0 - 3 + r, gx = x0 - 3 + c;
    uint2v out8 = {0u, 0u};
    if ((unsigned)gy < 56u && (unsigned)gx < 56u) {
      uint4v v = *(const uint4v*)(qbase + (size_t)(gy * 56 + gx) * 64 + g * 8);
      const u16* h = (const u16*)&v;
      float f[8];
#pragma unroll
      for (int e = 0; e < 8; e++) {
        unsigned u = ((unsigned)h[e]) << 16;
        f[e] = __builtin_bit_cast(float, u);
      }
      int lo = __builtin_amdgcn_cvt_pk_fp8_f32(f[0], f[1], 0, false);
      lo = __builtin_amdgcn_cvt_pk_fp8_f32(f[2], f[3], lo, true);
      int hi2 = __builtin_amdgcn_cvt_pk_fp8_f32(f[4], f[5], 0, false);
      hi2 = __builtin_amdgcn_cvt_pk_fp8_f32(f[6], f[7], hi2, true);
      out8[0] = lo; out8[1] = hi2;
    }
    *(uint2v*)&patchB[g * APL + lp * 8] = out8;
  }
  __syncthreads();

  int lane = tid & 63, wid = tid >> 6;
  int Mtile = wid & 1, Ntile = wid >> 1;
  int n = lane & 31, kgrp = lane >> 5;
  int py = Ntile * 4 + (n >> 3), px = n & 7;
  f32x16 acc;
#pragma unroll
  for (int i = 0; i < 16; i++) acc[i] = 0.f;

  const u8* Abase = wTb8 + (size_t)Mtile * 100352 + lane * 8;
  uint2v aP[4];
#pragma unroll
  for (int ch = 0; ch < 4; ch++)
    aP[ch] = *(const uint2v*)(Abase + ch * 512);
#pragma unroll
  for (int kh = 0; kh < 7; kh++) {
#pragma unroll
    for (int kw = 0; kw < 7; kw++) {
      int tap = kh * 7 + kw;
      int lp = (py + kh) * 14 + px + kw;
      uint2v aC[4];
#pragma unroll
      for (int ch = 0; ch < 4; ch++) aC[ch] = aP[ch];
      int ntap = (tap < 48) ? tap + 1 : 48;
      const u8* An = Abase + (size_t)(ntap * 4) * 512;
#pragma unroll
      for (int ch = 0; ch < 4; ch++)
        aP[ch] = *(const uint2v*)(An + ch * 512);
#pragma unroll
      for (int ch = 0; ch < 4; ch++) {
        int g = ch * 2 + kgrp;
        uint2v b8 = *(const uint2v*)&patchB[g * APL + lp * 8];
        acc = __builtin_amdgcn_mfma_f32_32x32x16_fp8_fp8(
            __builtin_bit_cast(long, aC[ch]), __builtin_bit_cast(long, b8),
            acc, 0, 0, 0);
      }
    }
  }

  // ---- fused tail: logits -> LDS, v-patch -> LDS, softmax, PV --------------
  __syncthreads();
  float* smx = (float*)shraw;            // [64 ko][64 px] fp32
  u16* vp = shraw + 8192;                // [196 pix][VPS] bf16
  int head = img % NHEADS;
#pragma unroll
  for (int r = 0; r < 16; r++) {
    int ko = Mtile * 32 + (r & 3) + 8 * (r >> 2) + 4 * kgrp;
    if (ko < KWIN)
      smx[ko * 64 + Ntile * 32 + n] = acc[r] + dm_b[ko] + rel_bias[ko * NHEADS + head];
  }
  const u16* vbase = vT + (size_t)img * PIX * 32;
  for (int idx = tid; idx < 784; idx += 256) {
    int g = idx & 3, lp = idx >> 2;
    int r = lp / 14, c = lp - r * 14;
    int gy = y0 - 3 + r, gx = x0 - 3 + c;
    uint4v val = {0u, 0u, 0u, 0u};
    if ((unsigned)gy < 56u && (unsigned)gx < 56u)
      val = *(const uint4v*)(vbase + (size_t)(gy * 56 + gx) * 32 + g * 8);
    *(uint4v*)&vp[lp * VPS + g * 8] = val;
  }
  __syncthreads();
  // wave-parallel softmax: thread (px = tid>>2, q4 = tid&3), shfl-xor width 4
  {
    int pxs = tid >> 2, q4 = tid & 3;
    int k0 = q4 * 13;
    int k1 = (q4 == 3) ? KWIN : k0 + 13;
    float m = -1e30f;
    for (int k = k0; k < k1; k++) m = fmaxf(m, smx[k * 64 + pxs]);
    m = fmaxf(m, __shfl_xor(m, 1, 64));
    m = fmaxf(m, __shfl_xor(m, 2, 64));
    float ssum = 0.f;
    for (int k = k0; k < k1; k++) {
      float e = __expf(smx[k * 64 + pxs] - m);
      smx[k * 64 + pxs] = e;
      ssum += e;
    }
    ssum += __shfl_xor(ssum, 1, 64);
    ssum += __shfl_xor(ssum, 2, 64);
    float inv = 1.f / ssum;
    for (int k = k0; k < k1; k++) smx[k * 64 + pxs] *= inv;
  }
  __syncthreads();
  int pxl = tid & 63, co = tid >> 6;
  int pyy = pxl >> 3, pxx = pxl & 7;
  float o8[8] = {0.f, 0.f, 0.f, 0.f, 0.f, 0.f, 0.f, 0.f};
#pragma unroll
  for (int kh = 0; kh < 7; kh++) {
#pragma unroll
    for (int kw = 0; kw < 7; kw++) {
      float p = smx[(kh * 7 + kw) * 64 + pxl];
      bf16x8 v = *(const bf16x8*)&vp[((pyy + kh) * 14 + pxx + kw) * VPS + co * 8];
#pragma unroll
      for (int j = 0; j < 8; j++) o8[j] += p * (float)v[j];
    }
  }
  int gp = (y0 + pyy) * 56 + x0 + pxx;
  int b = img / NHEADS;
  __hip_bfloat16 ob[8];
#pragma unroll
  for (int j = 0; j < 8; j++) ob[j] = __float2bfloat16(o8[j]);
  *(uint4v*)(attnoT + ((size_t)b * PIX + gp) * CDIM + head * 32 + co * 8) = *(uint4v*)ob;
}

// ---------------- launch ----------------------------------------------------
extern "C" void kernel_launch(void* const* d_in, const int* in_sizes, int n_in,
                              void* d_out, int out_size, void* d_ws, size_t ws_size,
                              hipStream_t stream) {
  const float* x        = (const float*)d_in[0];
  const float* bn_gamma = (const float*)d_in[1];
  const float* bn_beta  = (const float*)d_in[2];
  const float* qkv_w    = (const float*)d_in[3];
  const float* qkv_b    = (const float*)d_in[4];
  const float* dm_w     = (const float*)d_in[5];
  const float* dm_b     = (const float*)d_in[6];
  const float* rel_bias = (const float*)d_in[7];
  const float* proj_w   = (const float*)d_in[8];
  const float* proj_b   = (const float*)d_in[9];
  const float* c1_w     = (const float*)d_in[10];
  const float* c1_b     = (const float*)d_in[11];
  const float* c2_w     = (const float*)d_in[12];
  const float* c2_b     = (const float*)d_in[13];
  float* out = (float*)d_out;
  float* ws  = (float*)d_ws;

  float* stats   = ws;                          // 384 f
  float* b_eff   = stats + 384;                 // 576 f
  u16*   pk_qkv  = (u16*)(b_eff + 576);         // 110592 u16
  u16*   pk_proj = pk_qkv + 110592;             // 36864
  u16*   pk_c1   = pk_proj + 36864;             // 147456
  u16*   pk_c2   = pk_c1 + 147456;              // 147456
  u8*    wTb8    = (u8*)(pk_c2 + 147456);       // 200704 bytes (fp8)
  u16*   xT      = (u16*)(wTb8 + 200704);       // 2408448 u16
  u16*   qkT     = xT + 2408448;                // 4816896 u16
  u16*   vT      = qkT + 4816896;               // 2408448 u16
  u16*   attnoT  = vT + 2408448;                // 2408448 u16
  float* x1      = (float*)(attnoT + 2408448);  // 2408448 f
  u16*   x1T     = (u16*)(x1 + 2408448);        // 2408448 u16
  u16*   hT      = xT;  // alias: 9633792 u16 over dead xT+qkT+vT

  bn_stats_k<<<CDIM, 256, 0, stream>>>(x, stats);
  prep3_k<<<2122, 256, 0, stream>>>(dm_w, wTb8, proj_w, pk_proj, c1_w, pk_c1,
                                    c2_w, pk_c2, x, xT);
  fold_pack_k<<<576, 192, 0, stream>>>(qkv_w, qkv_b, bn_gamma, bn_beta, stats,
                                       pk_qkv, b_eff);

  mgemm_k<MG_QKV><<<dim3(49, 9), 256, 0, stream>>>(
      xT, pk_qkv, b_eff, nullptr, qkT, vT, nullptr, 192);
  attn_fused_k<<<NIMG * 49, 256, 0, stream>>>(qkT, wTb8, vT, dm_b, rel_bias, attnoT);
  mgemm_k<MG_PROJ><<<dim3(49, 3), 256, 0, stream>>>(
      attnoT, pk_proj, proj_b, x1, x1T, nullptr, x, 192);
  mgemm_k<MG_GELU><<<dim3(49, 12), 256, 0, stream>>>(
      x1T, pk_c1, c1_b, nullptr, hT, nullptr, nullptr, 192);
  mgemm_k<MG_C2><<<dim3(49, 3), 256, 0, stream>>>(
      hT, pk_c2, c2_b, out, nullptr, nullptr, x1, 768);
}